// Round 16
// baseline (442.145 us; speedup 1.0000x reference)
//
#include <hip/hip_runtime.h>
#include <hip/hip_bf16.h>

typedef __hip_bfloat16 bf16;
typedef __attribute__((ext_vector_type(8))) short short8;
typedef __attribute__((ext_vector_type(4))) float f32x4;

static __device__ __forceinline__ float b2f(bf16 v) { return __bfloat162float(v); }

static __device__ __forceinline__ float ldin(const void* p, long i, int bf) {
    return bf ? b2f(((const bf16*)p)[i]) : ((const float*)p)[i];
}

// ---------------- dtype detect ----------------
__global__ void detect_k(const unsigned short* __restrict__ x16, int* __restrict__ flag) {
    __shared__ int cnt[256];
    unsigned short u = x16[threadIdx.x];
    int e = (u >> 7) & 0xFF;
    cnt[threadIdx.x] = (e >= 100 && e <= 140) ? 1 : 0;
    __syncthreads();
    for (int off = 128; off > 0; off >>= 1) {
        if (threadIdx.x < off) cnt[threadIdx.x] += cnt[threadIdx.x + off];
        __syncthreads();
    }
    if (threadIdx.x == 0) *flag = (cnt[0] > 217) ? 1 : 0;
}

// ---------------- fused prep: 4 casts + w3 transpose + tap table ----------------
__global__ __launch_bounds__(384) void prep_k(
    const void* __restrict__ c1w, const void* __restrict__ s1w,
    const void* __restrict__ e1w, const void* __restrict__ w2,
    const void* __restrict__ w3, const void* __restrict__ mask,
    bf16* __restrict__ c1wb, bf16* __restrict__ hwb, bf16* __restrict__ w2b,
    bf16* __restrict__ w3b, int* __restrict__ tabd, float* __restrict__ tabw,
    const int* __restrict__ flagp)
{
    __shared__ char sm[16384];
    int bf = *flagp;
    int blk = blockIdx.x, tid = threadIdx.x;
    if (blk < 1024) {                      // cast c1w (393216)
        int idx = blk * 384 + tid;
        if (idx < 393216) c1wb[idx] = __float2bfloat16(ldin(c1w, idx, bf));
        return;
    }
    blk -= 1024;
    if (blk < 384) {                       // cast s1w (147456)
        int idx = blk * 384 + tid;
        if (idx < 147456) hwb[idx] = __float2bfloat16(ldin(s1w, idx, bf));
        return;
    }
    blk -= 384;
    if (blk < 384) {                       // cast e1w (147456)
        int idx = blk * 384 + tid;
        if (idx < 147456) hwb[147456 + idx] = __float2bfloat16(ldin(e1w, idx, bf));
        return;
    }
    blk -= 384;
    if (blk < 171) {                       // cast w2 (65536)
        int idx = blk * 384 + tid;
        if (idx < 65536) w2b[idx] = __float2bfloat16(ldin(w2, idx, bf));
        return;
    }
    blk -= 171;
    if (blk < 512) {                       // transpose w3 -> w3b[n][h3][c]
        int h3 = blk;
        bf16* t = (bf16*)sm;
        long base = (long)h3 * 8192;
        for (int i = tid; i < 8192; i += 384)
            t[i] = __float2bfloat16(ldin(w3, base + i, bf));
        __syncthreads();
        for (int i = tid; i < 8192; i += 384) {
            int n = i >> 8, c = i & 255;
            w3b[((long)n * 512 + h3) * 256 + c] = t[c * 32 + n];
        }
        return;
    }
    blk -= 512;
    {                                      // build_table (256 blocks, 384 thr)
        int nw = blk;
        int w = nw >> 5, n = nw & 31;
        int d = tid - 165;
        float v = 0.f;
        if (d <= 165) {
            if (d < 0) v = ldin(mask, (long)(254 + d) * 65536 + ((long)n * 256 + 254) * 8 + w, bf);
            else       v = ldin(mask, (long)(1 + d) * 65536 + ((long)n * 256 + 1) * 8 + w, bf);
        }
        unsigned char* nz = (unsigned char*)sm;
        nz[tid] = (v != 0.f) ? 1 : 0;
        if (tid < 6) { tabd[nw * 6 + tid] = 0; tabw[nw * 6 + tid] = 0.f; }
        __syncthreads();
        if (v != 0.f) {
            int slot = 0;
            for (int j = 0; j < tid; ++j) slot += nz[j];
            if (slot < 6) { tabd[nw * 6 + slot] = d; tabw[nw * 6 + slot] = v; }
        }
    }
}

__global__ void build_corr_k(const void* __restrict__ mask, const int* __restrict__ tabd,
                             const float* __restrict__ tabw, float* __restrict__ corrB,
                             const int* __restrict__ flagp) {
    int bf = *flagp;
    int idx = blockIdx.x * 256 + threadIdx.x;   // 65536
    if (idx >= 65536) return;
    int n = idx >> 11, p = idx & 2047;
    int t = p >> 3, w = p & 7;
    float mv = ldin(mask, ((long)n * 256 + t) * 8 + w, bf);
    float sub = 0.f;
    int base = (w * 32 + n) * 6;
    for (int k = 0; k < 6; ++k)
        if (tabd[base + k] == -t && tabw[base + k] != 0.f) sub += tabw[base + k];
    corrB[idx] = mv - sub;
}

// ---------------- bf16 im2col ----------------
__global__ void im2col_xb_k(const void* __restrict__ x, bf16* __restrict__ out,
                            const int* __restrict__ flagp) {
    int bf = *flagp;
    int idx = blockIdx.x * 256 + threadIdx.x;   // 786432
    if (idx >= 786432) return;
    int b = idx / 393216;
    int rem = idx - b * 393216;
    int t = rem / 1536, k = rem - t * 1536;
    int c = k / 3, q = k - c * 3;
    int tt = t + q - 1;
    float v = (tt >= 0 && tt < 256) ? ldin(x, ((long)b * 512 + c) * 256 + tt, bf) : 0.f;
    out[idx] = __float2bfloat16(v);
}

__global__ void im2col_fb_k(const float* __restrict__ f, bf16* __restrict__ out) {
    int idx = blockIdx.x * 256 + threadIdx.x;   // 4718592
    if (idx >= 4718592) return;
    int b = idx / 2359296;
    int rem = idx - b * 2359296;
    int p = rem / 1152, k = rem - p * 1152;
    int c = k / 9, q = k - c * 9;
    int dy = q / 3, dx = q - dy * 3;
    int t = p >> 3, w = p & 7;
    int tt = t + dy - 1, ww = w + dx - 1;
    float v = (tt >= 0 && tt < 256 && ww >= 0 && ww < 8)
                  ? f[((long)b * 128 + c) * 2048 + tt * 8 + ww] : 0.f;
    out[idx] = __float2bfloat16(v);
}

// yT[b][p][c] (bf16) from y[b][c=512][p=2048] (fp32), 64x64 LDS tile
__global__ __launch_bounds__(256) void castT_k(const float* __restrict__ y,
                                               bf16* __restrict__ yT) {
    int p0 = blockIdx.x * 64, c0 = blockIdx.y * 64, b = blockIdx.z;
    __shared__ bf16 t[64][65];
    const float* src = y + (long)b * 1048576;
    for (int i = threadIdx.x; i < 4096; i += 256) {
        int cl = i >> 6, pl = i & 63;
        t[pl][cl] = __float2bfloat16(src[(long)(c0 + cl) * 2048 + p0 + pl]);
    }
    __syncthreads();
    bf16* dst = yT + (long)b * 1048576;
    for (int i = threadIdx.x; i < 4096; i += 256) {
        int pl = i >> 6, cl = i & 63;
        dst[(long)(p0 + pl) * 512 + c0 + cl] = t[pl][cl];
    }
}

// ---------------- generic weight-GEMM via MFMA ----------------
template<int NT>
__global__ __launch_bounds__(256) void wgemm_mfma(
    const bf16* __restrict__ A, const bf16* __restrict__ B, float* __restrict__ C,
    const void* __restrict__ bias1, const void* __restrict__ bias2,
    int M, int K, int P, int a_div, long a_zs, const int* __restrict__ flagp)
{
    int bf = *flagp;
    int z = blockIdx.z;
    const bf16* A2 = A + (long)(z / a_div) * a_zs;
    const bf16* B2 = B + (long)(z & 1) * (long)P * K;
    float* C2 = C + (long)z * M * P;
    const void* bi = (z / a_div) ? bias2 : bias1;

    int tid = threadIdx.x;
    int wv = tid >> 6, lane = tid & 63;
    int q = lane >> 4, col = lane & 15;
    int m0 = blockIdx.y * 64 + wv * 16;
    int p0 = blockIdx.x * (16 * NT);

    f32x4 acc[NT];
    #pragma unroll
    for (int i = 0; i < NT; ++i) acc[i] = (f32x4){0.f, 0.f, 0.f, 0.f};

    const short8* Ab = (const short8*)(A2 + (long)(m0 + col) * K);
    int kch = K >> 5;
    for (int kc = 0; kc < kch; ++kc) {
        short8 af = Ab[kc * 4 + q];
        #pragma unroll
        for (int nt = 0; nt < NT; ++nt) {
            const short8* Bb = (const short8*)(B2 + (long)(p0 + nt * 16 + col) * K);
            short8 bfr = Bb[kc * 4 + q];
            acc[nt] = __builtin_amdgcn_mfma_f32_16x16x32_bf16(af, bfr, acc[nt], 0, 0, 0);
        }
    }

    float bv[4];
    #pragma unroll
    for (int r = 0; r < 4; ++r) bv[r] = ldin(bi, m0 + q * 4 + r, bf);
    #pragma unroll
    for (int nt = 0; nt < NT; ++nt)
        #pragma unroll
        for (int r = 0; r < 4; ++r)
            C2[(long)(m0 + q * 4 + r) * P + p0 + nt * 16 + col] = acc[nt][r] + bv[r];
}

// ---------------- MFMA P-GEMM ----------------
__global__ __launch_bounds__(256) void pgemm_mfma(
    const bf16* __restrict__ w3b, const bf16* __restrict__ hbT,
    float* __restrict__ P)
{
    int z = blockIdx.z;          // b*32 + n
    int b = z >> 5, n = z & 31;
    int bm = blockIdx.y;         // 0..7
    int tid = threadIdx.x;
    int wv = tid >> 6, lane = tid & 63;
    int q = lane >> 4, col = lane & 15;

    f32x4 acc[16];
    #pragma unroll
    for (int i = 0; i < 16; ++i) acc[i] = (f32x4){0.f, 0.f, 0.f, 0.f};

    const short8* Abase = (const short8*)(w3b + ((long)n * 512 + bm * 64 + wv * 16 + col) * 256);
    const short8* Bbase = (const short8*)(hbT + (long)b * 65536);

    #pragma unroll
    for (int kc = 0; kc < 8; ++kc) {
        short8 af = Abase[kc * 4 + q];
        #pragma unroll
        for (int nt = 0; nt < 16; ++nt) {
            short8 bfr = Bbase[(nt * 16 + col) * 32 + kc * 4 + q];
            acc[nt] = __builtin_amdgcn_mfma_f32_16x16x32_bf16(af, bfr, acc[nt], 0, 0, 0);
        }
    }

    long dbase = (long)b * 4194304 + (long)n * 256 +
                 (long)(bm * 64 + wv * 16 + q * 4) * 8192 + col;
    #pragma unroll
    for (int nt = 0; nt < 16; ++nt)
        #pragma unroll
        for (int r = 0; r < 4; ++r)
            P[dbase + (long)r * 8192 + nt * 16] = acc[nt][r];
}

// ---------------- GN1 (h) + ReLU + fused bf16 transpose-cast to hbT ----------------
__global__ __launch_bounds__(1024) void gn_relu_h_k(
    float* __restrict__ h, bf16* __restrict__ hbT,
    const void* __restrict__ g, const void* __restrict__ bt,
    const int* __restrict__ flagp)
{
    int bf = *flagp;
    int gid = blockIdx.x;                // 64 = b*32 + gr
    int b = gid >> 5, gr = gid & 31;
    float* base = h + ((long)b * 256 + gr * 8) * 256;   // cpg=8, S=256, cnt=2048
    double s = 0.0, s2 = 0.0;
    for (int i = threadIdx.x; i < 2048; i += 1024) {
        float v = base[i];
        s += v; s2 += (double)v * v;
    }
    __shared__ double rs[1024], rq[1024];
    rs[threadIdx.x] = s; rq[threadIdx.x] = s2;
    __syncthreads();
    for (int off = 512; off > 0; off >>= 1) {
        if (threadIdx.x < off) { rs[threadIdx.x] += rs[threadIdx.x + off]; rq[threadIdx.x] += rq[threadIdx.x + off]; }
        __syncthreads();
    }
    double mean_d = rs[0] / 2048.0;
    float mean = (float)mean_d;
    float var = (float)(rq[0] / 2048.0 - mean_d * mean_d);
    float rstd = rsqrtf(var + 1e-5f);
    for (int i = threadIdx.x; i < 2048; i += 1024) {
        int c = gr * 8 + (i >> 8), tau = i & 255;
        float v = (base[i] - mean) * rstd * ldin(g, c, bf) + ldin(bt, c, bf);
        v = v > 0.f ? v : 0.f;
        base[i] = v;
        hbT[(long)b * 65536 + tau * 256 + c] = __float2bfloat16(v);
    }
}

// ---------------- GN: two-phase generic ----------------
__global__ __launch_bounds__(256) void gn_part_k(
    const float* __restrict__ buf, double* __restrict__ part,
    int C, int S, int groups, int chunks)
{
    int gi = blockIdx.x / chunks, ch = blockIdx.x % chunks;
    int b = gi / groups, gr = gi % groups;
    int cpg = C / groups;
    long cnt = (long)cpg * S;
    long clen = cnt / chunks;
    const float* base = buf + ((long)b * C + (long)gr * cpg) * S + (long)ch * clen;
    double s = 0.0, s2 = 0.0;
    for (long i = threadIdx.x; i < clen; i += 256) {
        float v = base[i];
        s += v; s2 += (double)v * v;
    }
    __shared__ double rs[256], rq[256];
    rs[threadIdx.x] = s; rq[threadIdx.x] = s2;
    __syncthreads();
    for (int off = 128; off > 0; off >>= 1) {
        if (threadIdx.x < off) { rs[threadIdx.x] += rs[threadIdx.x + off]; rq[threadIdx.x] += rq[threadIdx.x + off]; }
        __syncthreads();
    }
    if (threadIdx.x == 0) { part[blockIdx.x * 2] = rs[0]; part[blockIdx.x * 2 + 1] = rq[0]; }
}

__global__ __launch_bounds__(256) void gn_apply_k(
    float* __restrict__ buf, const double* __restrict__ part,
    const void* __restrict__ g, const void* __restrict__ bt,
    int C, int S, int groups, int chunks, const int* __restrict__ flagp)
{
    int bf = *flagp;
    int gi = blockIdx.x / chunks, ch = blockIdx.x % chunks;
    int b = gi / groups, gr = gi % groups;
    int cpg = C / groups;
    long cnt = (long)cpg * S;
    long clen = cnt / chunks;
    double s = 0.0, s2 = 0.0;
    for (int k = 0; k < chunks; ++k) {
        s += part[(gi * chunks + k) * 2];
        s2 += part[(gi * chunks + k) * 2 + 1];
    }
    double mean_d = s / (double)cnt;
    float mean = (float)mean_d;
    float var = (float)(s2 / (double)cnt - mean_d * mean_d);
    float rstd = rsqrtf(var + 1e-5f);
    float* base = buf + ((long)b * C + (long)gr * cpg) * S + (long)ch * clen;
    long off0 = (long)ch * clen;
    for (long i = threadIdx.x; i < clen; i += 256) {
        int c = gr * cpg + (int)((off0 + i) / S);
        float v = (base[i] - mean) * rstd * ldin(g, c, bf) + ldin(bt, c, bf);
        base[i] = v > 0.f ? v : 0.f;
    }
}

// gn_apply for the concatenated t1s/t1e pair: b in 0..3, gamma by b>=2
__global__ __launch_bounds__(256) void gn_apply2_k(
    float* __restrict__ buf, const double* __restrict__ part,
    const void* __restrict__ g1, const void* __restrict__ b1,
    const void* __restrict__ g2, const void* __restrict__ b2,
    int chunks, const int* __restrict__ flagp)
{
    int bf = *flagp;
    int gi = blockIdx.x / chunks, ch = blockIdx.x % chunks;
    int b = gi >> 5, gr = gi & 31;       // C=128, groups=32, cpg=4, S=2048
    const void* g = (b >= 2) ? g2 : g1;
    const void* bt = (b >= 2) ? b2 : b1;
    long cnt = 8192, clen = cnt / chunks;
    double s = 0.0, s2 = 0.0;
    for (int k = 0; k < chunks; ++k) {
        s += part[(gi * chunks + k) * 2];
        s2 += part[(gi * chunks + k) * 2 + 1];
    }
    double mean_d = s / (double)cnt;
    float mean = (float)mean_d;
    float var = (float)(s2 / (double)cnt - mean_d * mean_d);
    float rstd = rsqrtf(var + 1e-5f);
    float* base = buf + ((long)b * 128 + gr * 4) * 2048 + (long)ch * clen;
    long off0 = (long)ch * clen;
    for (long i = threadIdx.x; i < clen; i += 256) {
        int c = gr * 4 + (int)((off0 + i) >> 11);
        float v = (base[i] - mean) * rstd * ldin(g, c, bf) + ldin(bt, c, bf);
        base[i] = v > 0.f ? v : 0.f;
    }
}

// ---------------- sparse mask apply (partial halves) ----------------
__global__ __launch_bounds__(256) void apply_y_k(
    const float* __restrict__ P, const int* __restrict__ tabd,
    const float* __restrict__ tabw, float* __restrict__ part,
    const int* __restrict__ flagp)
{
    int bx = blockIdx.x;                 // 0..1023
    int h3 = bx >> 1, half = bx & 1;
    int n0 = half * 16;
    __shared__ float2 Pl2[16 * 256];
    __shared__ float4 Tp4[384];
    const float4* p04 = (const float4*)(P + ((long)h3 * 32 + n0) * 256);
    const float4* p14 = (const float4*)(P + ((long)(512 + h3) * 32 + n0) * 256);
    float4* pl4 = (float4*)Pl2;
    for (int i = threadIdx.x; i < 1024; i += 256) {
        float4 a = p04[i], b = p14[i];
        pl4[i * 2]     = make_float4(a.x, b.x, a.y, b.y);
        pl4[i * 2 + 1] = make_float4(a.z, b.z, a.w, b.w);
    }
    float2* tp2 = (float2*)Tp4;
    for (int i = threadIdx.x; i < 768; i += 256) {
        int el = i / 6, k = i - el * 6;
        int ge = ((el >> 4) << 5) + n0 + (el & 15);
        tp2[i] = make_float2(tabw[ge * 6 + k], __int_as_float(tabd[ge * 6 + k]));
    }
    __syncthreads();

    int t = threadIdx.x;
    float a0[8], a1[8];
    #pragma unroll
    for (int w = 0; w < 8; ++w) { a0[w] = 0.f; a1[w] = 0.f; }

    #pragma unroll 1
    for (int nl = 0; nl < 16; ++nl) {
        const float2* Pn = Pl2 + (nl << 8);
        #pragma unroll
        for (int w = 0; w < 8; ++w) {
            int e4 = ((w << 4) + nl) * 3;
            float4 q0 = Tp4[e4], q1 = Tp4[e4 + 1], q2 = Tp4[e4 + 2];
            float wts[6] = {q0.x, q0.z, q1.x, q1.z, q2.x, q2.z};
            int   dss[6] = {__float_as_int(q0.y), __float_as_int(q0.w),
                            __float_as_int(q1.y), __float_as_int(q1.w),
                            __float_as_int(q2.y), __float_as_int(q2.w)};
            #pragma unroll
            for (int k = 0; k < 6; ++k) {
                int tau = t + dss[k];
                int idx = tau & 255;
                float wt = ((unsigned)tau < 256u) ? wts[k] : 0.f;
                float2 pv = Pn[idx];
                a0[w] += wt * pv.x;
                a1[w] += wt * pv.y;
            }
        }
    }

    long y0 = (long)half * 2097152 + (long)h3 * 2048 + (long)t * 8;
    long y1 = y0 + 512L * 2048;
    *(float4*)(part + y0)     = make_float4(a0[0], a0[1], a0[2], a0[3]);
    *(float4*)(part + y0 + 4) = make_float4(a0[4], a0[5], a0[6], a0[7]);
    *(float4*)(part + y1)     = make_float4(a1[0], a1[1], a1[2], a1[3]);
    *(float4*)(part + y1 + 4) = make_float4(a1[4], a1[5], a1[6], a1[7]);
}

// GN3 phase 1 fused with merge: v = part0+part1+bias+corr.P0 ; y=v ; stats
__global__ __launch_bounds__(256) void gn3_part_k(
    const float* __restrict__ ypart, const float* __restrict__ P,
    const float* __restrict__ corrB, const void* __restrict__ r3b,
    float* __restrict__ y, double* __restrict__ part,
    const int* __restrict__ flagp)
{
    int bf = *flagp;
    int gi = blockIdx.x >> 3, ch = blockIdx.x & 7;   // chunks=8
    int b = gi >> 5, gr = gi & 31;                   // C=512, cpg=16, S=2048
    long e0 = ((long)b * 512 + gr * 16) * 2048 + (long)ch * 4096;
    double s = 0.0, s2 = 0.0;
    for (int i = threadIdx.x; i < 4096; i += 256) {
        long e = e0 + i;
        int loc = ch * 4096 + i;
        int h3 = gr * 16 + (loc >> 11);
        int p = loc & 2047;
        float v = ypart[e] + ypart[2097152 + e] + ldin(r3b, h3, bf);
        const float* p0 = P + ((long)(b * 512 + h3) * 32) * 256;
        #pragma unroll 4
        for (int n = 0; n < 32; ++n)
            v += p0[n * 256] * corrB[n * 2048 + p];
        y[e] = v;
        s += v; s2 += (double)v * v;
    }
    __shared__ double rs[256], rq[256];
    rs[threadIdx.x] = s; rq[threadIdx.x] = s2;
    __syncthreads();
    for (int off = 128; off > 0; off >>= 1) {
        if (threadIdx.x < off) { rs[threadIdx.x] += rs[threadIdx.x + off]; rq[threadIdx.x] += rq[threadIdx.x + off]; }
        __syncthreads();
    }
    if (threadIdx.x == 0) { part[blockIdx.x * 2] = rs[0]; part[blockIdx.x * 2 + 1] = rq[0]; }
}

__global__ __launch_bounds__(64) void head_out_k(
    const float* __restrict__ t1s, const float* __restrict__ t1e,
    const void* __restrict__ s2w, const void* __restrict__ s2b,
    const void* __restrict__ e2w, const void* __restrict__ e2b,
    void* __restrict__ out, const int* __restrict__ flagp) {
    int bf = *flagp;
    int idx = blockIdx.x * 64 + threadIdx.x;   // 4096
    if (idx >= 4096) return;
    int b = idx >> 11, p = idx & 2047;
    const float* ts = t1s + (long)b * 262144 + p;
    const float* te = t1e + (long)b * 262144 + p;
    float as = ldin(s2b, 0, bf), ae = ldin(e2b, 0, bf);
    #pragma unroll 8
    for (int c = 0; c < 128; ++c) {
        as += ldin(s2w, c, bf) * ts[(long)c * 2048];
        ae += ldin(e2w, c, bf) * te[(long)c * 2048];
    }
    float vs = 1.f / (1.f + expf(-as));
    float ve = 1.f / (1.f + expf(-ae));
    long o0 = ((long)b * 2) * 2048 + p;
    long o1 = ((long)b * 2 + 1) * 2048 + p;
    if (bf) {
        ((bf16*)out)[o0] = __float2bfloat16(vs);
        ((bf16*)out)[o1] = __float2bfloat16(ve);
    } else {
        ((float*)out)[o0] = vs;
        ((float*)out)[o1] = ve;
    }
}

// ---------------- launch ----------------
extern "C" void kernel_launch(void* const* d_in, const int* in_sizes, int n_in,
                              void* d_out, int out_size, void* d_ws, size_t ws_size,
                              hipStream_t stream) {
    const void* x    = d_in[0];
    const void* mask = d_in[1];
    const void* c1w  = d_in[2];
    const void* c1b  = d_in[3];
    const void* gn1g = d_in[4];
    const void* gn1b = d_in[5];
    const void* w3   = d_in[6];
    const void* r3b  = d_in[7];
    const void* gn3g = d_in[8];
    const void* gn3b = d_in[9];
    const void* w2   = d_in[10];
    const void* r2b  = d_in[11];
    const void* gn2g = d_in[12];
    const void* gn2b = d_in[13];
    const void* s1w  = d_in[14];
    const void* s1b  = d_in[15];
    const void* sgng = d_in[16];
    const void* sgnb = d_in[17];
    const void* s2w  = d_in[18];
    const void* s2b  = d_in[19];
    const void* e1w  = d_in[20];
    const void* e1b  = d_in[21];
    const void* egng = d_in[22];
    const void* egnb = d_in[23];
    const void* e2w  = d_in[24];
    const void* e2b  = d_in[25];
    float* ws = (float*)d_ws;

    int*   flagI = (int*)(ws + 0);       // 64 reserved
    float* h     = ws + 64;              // 131072
    float* c1t   = ws + 131136;          // 393216 (c1wb bf16)
    float* w2t   = ws + 524352;          // 65536 (w2b bf16)
    float* s1t   = ws + 589888;          // 294912 (s1wb+e1wb bf16)
    float* corrB = ws + 884800;          // 65536
    float* tabw  = ws + 950336;          // 1536
    int*   tabd  = (int*)(ws + 951872);  // 1536
    float* t1s   = ws + 986176;          // 524288
    float* t1e   = ws + 1510464;         // 524288 (contiguous after t1s)
    float* f     = ws + 2034752;         // 524288
    float* y     = ws + 2559040;         // 2097152
    float* w3reg = ws + 4656192;         // 4194304 (bf16 bufs / apply partials)
    float* Pb    = ws + 8850496;         // 8388608
    double* gnbuf = (double*)(ws + 17239104); // 1024 doubles
    bf16*  w3b   = (bf16*)w3reg;
    bf16*  hbT   = (bf16*)(w3reg + 2097152);
    bf16*  c1wb  = (bf16*)c1t;
    bf16*  w2b   = (bf16*)w2t;
    bf16*  hwb   = (bf16*)s1t;
    bf16*  colxb = (bf16*)y;                       // y dead until gn3_part
    bf16*  fcolb = (bf16*)Pb;
    bf16*  yT    = (bf16*)(Pb + 4194304);          // Pb tail (P dead post-GN3)
    float* ypart = w3reg;                          // 4M floats (w3b/hbT dead post-pgemm)

    dim3 blk(256);

    detect_k<<<dim3(1), blk, 0, stream>>>((const unsigned short*)x, flagI);

    // fused prep (casts + w3 transpose + tap table), then corr
    prep_k<<<dim3(2731), dim3(384), 0, stream>>>(
        c1w, s1w, e1w, w2, w3, mask, c1wb, hwb, w2b, w3b, tabd, tabw, flagI);
    build_corr_k<<<dim3(256), blk, 0, stream>>>(mask, tabd, tabw, corrB, flagI);

    // conv1 via MFMA + GN1(+fused hbT cast)
    im2col_xb_k<<<dim3(3072), blk, 0, stream>>>(x, colxb, flagI);
    wgemm_mfma<1><<<dim3(16, 4, 2), blk, 0, stream>>>(
        c1wb, colxb, h, c1b, c1b, 256, 1536, 256, 1, 0L, flagI);
    gn_relu_h_k<<<dim3(64), dim3(1024), 0, stream>>>(h, hbT, gn1g, gn1b, flagI);

    // P-GEMM via bf16 MFMA
    pgemm_mfma<<<dim3(1, 8, 64), blk, 0, stream>>>(w3b, hbT, Pb);

    // sparse mask apply + GN3 (phase1 fused with merge+bias+corr)
    apply_y_k<<<dim3(1024), blk, 0, stream>>>(Pb, tabd, tabw, ypart, flagI);
    gn3_part_k<<<dim3(512), blk, 0, stream>>>(ypart, Pb, corrB, r3b, y, gnbuf, flagI);
    gn_apply_k<<<dim3(512), blk, 0, stream>>>(y, gnbuf, gn3g, gn3b, 512, 2048, 32, 8, flagI);

    // r2d via MFMA + GN2 (2-phase)
    castT_k<<<dim3(32, 8, 2), blk, 0, stream>>>(y, yT);
    wgemm_mfma<2><<<dim3(64, 2, 2), blk, 0, stream>>>(
        w2b, yT, f, r2b, r2b, 128, 512, 2048, 2, 0L, flagI);
    gn_part_k<<<dim3(256), blk, 0, stream>>>(f, gnbuf, 128, 2048, 32, 4);
    gn_apply_k<<<dim3(256), blk, 0, stream>>>(f, gnbuf, gn2g, gn2b, 128, 2048, 32, 4, flagI);

    // heads via MFMA + combined GN over t1s|t1e (B=4)
    im2col_fb_k<<<dim3(18432), blk, 0, stream>>>(f, fcolb);
    wgemm_mfma<4><<<dim3(32, 2, 4), blk, 0, stream>>>(
        hwb, fcolb, t1s, s1b, e1b, 128, 1152, 2048, 2, 147456L, flagI);
    gn_part_k<<<dim3(512), blk, 0, stream>>>(t1s, gnbuf, 128, 2048, 32, 4);
    gn_apply2_k<<<dim3(512), blk, 0, stream>>>(t1s, gnbuf, sgng, sgnb, egng, egnb, 4, flagI);

    // 1x1 head convs + sigmoid -> output
    head_out_k<<<dim3(64), dim3(64), 0, stream>>>(t1s, t1e, s2w, s2b, e2w, e2b, d_out, flagI);
}

// Round 17
// 440.998 us; speedup vs baseline: 1.0026x; 1.0026x over previous
//
#include <hip/hip_runtime.h>
#include <hip/hip_bf16.h>

typedef __hip_bfloat16 bf16;
typedef __attribute__((ext_vector_type(8))) short short8;
typedef __attribute__((ext_vector_type(4))) float f32x4;

static __device__ __forceinline__ float b2f(bf16 v) { return __bfloat162float(v); }

static __device__ __forceinline__ float ldin(const void* p, long i, int bf) {
    return bf ? b2f(((const bf16*)p)[i]) : ((const float*)p)[i];
}

// ---------------- dtype detect ----------------
__global__ void detect_k(const unsigned short* __restrict__ x16, int* __restrict__ flag) {
    __shared__ int cnt[256];
    unsigned short u = x16[threadIdx.x];
    int e = (u >> 7) & 0xFF;
    cnt[threadIdx.x] = (e >= 100 && e <= 140) ? 1 : 0;
    __syncthreads();
    for (int off = 128; off > 0; off >>= 1) {
        if (threadIdx.x < off) cnt[threadIdx.x] += cnt[threadIdx.x + off];
        __syncthreads();
    }
    if (threadIdx.x == 0) *flag = (cnt[0] > 217) ? 1 : 0;
}

// ---------------- casts / transposes ----------------
__global__ void cast_bf_k(const void* __restrict__ in, bf16* __restrict__ out,
                          int n, const int* __restrict__ flagp) {
    int bf = *flagp;
    int idx = blockIdx.x * 256 + threadIdx.x;
    if (idx >= n) return;
    out[idx] = __float2bfloat16(ldin(in, idx, bf));
}

// w3b[n][h3][c] (bf16) from w3[(h3*256+c)*32+n]
__global__ __launch_bounds__(256) void transpose_w3b_k(const void* __restrict__ w3,
                                                       bf16* __restrict__ out,
                                                       const int* __restrict__ flagp) {
    int bf = *flagp;
    int h3 = blockIdx.x;     // 512
    __shared__ bf16 t[8192];
    long base = (long)h3 * 8192;
    for (int i = threadIdx.x; i < 8192; i += 256)
        t[i] = __float2bfloat16(ldin(w3, base + i, bf));
    __syncthreads();
    for (int i = threadIdx.x; i < 8192; i += 256) {
        int n = i >> 8, c = i & 255;
        out[((long)n * 512 + h3) * 256 + c] = t[c * 32 + n];
    }
}

// hbT[b][tau][c] (bf16) from h[b][c][tau] (fp32)
__global__ void cast_hT_k(const float* __restrict__ h, bf16* __restrict__ out) {
    int idx = blockIdx.x * 256 + threadIdx.x;   // 131072
    if (idx >= 131072) return;
    int b = idx >> 16, r = idx & 65535;
    int tau = r >> 8, c = r & 255;
    out[idx] = __float2bfloat16(h[b * 65536 + c * 256 + tau]);
}

// yT[b][p][c] (bf16) from y[b][c=512][p=2048] (fp32), 64x64 LDS tile
__global__ __launch_bounds__(256) void castT_k(const float* __restrict__ y,
                                               bf16* __restrict__ yT) {
    int p0 = blockIdx.x * 64, c0 = blockIdx.y * 64, b = blockIdx.z;
    __shared__ bf16 t[64][65];
    const float* src = y + (long)b * 1048576;
    for (int i = threadIdx.x; i < 4096; i += 256) {
        int cl = i >> 6, pl = i & 63;
        t[pl][cl] = __float2bfloat16(src[(long)(c0 + cl) * 2048 + p0 + pl]);
    }
    __syncthreads();
    bf16* dst = yT + (long)b * 1048576;
    for (int i = threadIdx.x; i < 4096; i += 256) {
        int pl = i >> 6, cl = i & 63;
        dst[(long)(p0 + pl) * 512 + c0 + cl] = t[pl][cl];
    }
}

// ---------------- bf16 im2col ----------------
__global__ void im2col_xb_k(const void* __restrict__ x, bf16* __restrict__ out,
                            const int* __restrict__ flagp) {
    int bf = *flagp;
    int idx = blockIdx.x * 256 + threadIdx.x;   // 786432
    if (idx >= 786432) return;
    int b = idx / 393216;
    int rem = idx - b * 393216;
    int t = rem / 1536, k = rem - t * 1536;
    int c = k / 3, q = k - c * 3;
    int tt = t + q - 1;
    float v = (tt >= 0 && tt < 256) ? ldin(x, ((long)b * 512 + c) * 256 + tt, bf) : 0.f;
    out[idx] = __float2bfloat16(v);
}

// LDS-tiled im2col for f: coalesced reads + contiguous k-run writes.
// block: z=b, y=c-tile(4 x 32c), x=p-tile(32 x 64p)
__global__ __launch_bounds__(256) void im2col_fb_t(const float* __restrict__ f,
                                                   bf16* __restrict__ out) {
    int b = blockIdx.z, c0 = blockIdx.y * 32, p0 = blockIdx.x * 64;
    int t0 = p0 >> 3;
    __shared__ float tile[32][80];   // [cl][(tt-(t0-1))*8 + ww]
    for (int i = threadIdx.x; i < 2560; i += 256) {
        int cl = i / 80, pos = i - cl * 80;
        int tt = t0 - 1 + (pos >> 3), ww = pos & 7;
        float v = (tt >= 0 && tt < 256)
                      ? f[((long)b * 128 + c0 + cl) * 2048 + tt * 8 + ww] : 0.f;
        tile[cl][pos] = v;
    }
    __syncthreads();
    for (int i = threadIdx.x; i < 18432; i += 256) {   // 64 p x 288 k
        int pl = i / 288, kl = i - pl * 288;
        int cl = kl / 9, q = kl - cl * 9;
        int dy = q / 3, dx = q - dy * 3;
        int p = p0 + pl;
        int t = p >> 3, w = p & 7;
        int ww = w + dx - 1;
        float v = (ww >= 0 && ww < 8) ? tile[cl][(t + dy - t0) * 8 + ww] : 0.f;
        out[((long)b * 2048 + p) * 1152 + c0 * 9 + kl] = __float2bfloat16(v);
    }
}

// ---------------- generic weight-GEMM via MFMA ----------------
template<int NT>
__global__ __launch_bounds__(256) void wgemm_mfma(
    const bf16* __restrict__ A, const bf16* __restrict__ B, float* __restrict__ C,
    const void* __restrict__ bias1, const void* __restrict__ bias2,
    int M, int K, int P, int a_div, long a_zs, const int* __restrict__ flagp)
{
    int bf = *flagp;
    int z = blockIdx.z;
    const bf16* A2 = A + (long)(z / a_div) * a_zs;
    const bf16* B2 = B + (long)(z & 1) * (long)P * K;
    float* C2 = C + (long)z * M * P;
    const void* bi = (z / a_div) ? bias2 : bias1;

    int tid = threadIdx.x;
    int wv = tid >> 6, lane = tid & 63;
    int q = lane >> 4, col = lane & 15;
    int m0 = blockIdx.y * 64 + wv * 16;
    int p0 = blockIdx.x * (16 * NT);

    f32x4 acc[NT];
    #pragma unroll
    for (int i = 0; i < NT; ++i) acc[i] = (f32x4){0.f, 0.f, 0.f, 0.f};

    const short8* Ab = (const short8*)(A2 + (long)(m0 + col) * K);
    int kch = K >> 5;
    for (int kc = 0; kc < kch; ++kc) {
        short8 af = Ab[kc * 4 + q];
        #pragma unroll
        for (int nt = 0; nt < NT; ++nt) {
            const short8* Bb = (const short8*)(B2 + (long)(p0 + nt * 16 + col) * K);
            short8 bfr = Bb[kc * 4 + q];
            acc[nt] = __builtin_amdgcn_mfma_f32_16x16x32_bf16(af, bfr, acc[nt], 0, 0, 0);
        }
    }

    float bv[4];
    #pragma unroll
    for (int r = 0; r < 4; ++r) bv[r] = ldin(bi, m0 + q * 4 + r, bf);
    #pragma unroll
    for (int nt = 0; nt < NT; ++nt)
        #pragma unroll
        for (int r = 0; r < 4; ++r)
            C2[(long)(m0 + q * 4 + r) * P + p0 + nt * 16 + col] = acc[nt][r] + bv[r];
}

// ---------------- MFMA P-GEMM ----------------
__global__ __launch_bounds__(256) void pgemm_mfma(
    const bf16* __restrict__ w3b, const bf16* __restrict__ hbT,
    float* __restrict__ P)
{
    int z = blockIdx.z;          // b*32 + n
    int b = z >> 5, n = z & 31;
    int bm = blockIdx.y;         // 0..7
    int tid = threadIdx.x;
    int wv = tid >> 6, lane = tid & 63;
    int q = lane >> 4, col = lane & 15;

    f32x4 acc[16];
    #pragma unroll
    for (int i = 0; i < 16; ++i) acc[i] = (f32x4){0.f, 0.f, 0.f, 0.f};

    const short8* Abase = (const short8*)(w3b + ((long)n * 512 + bm * 64 + wv * 16 + col) * 256);
    const short8* Bbase = (const short8*)(hbT + (long)b * 65536);

    #pragma unroll
    for (int kc = 0; kc < 8; ++kc) {
        short8 af = Abase[kc * 4 + q];
        #pragma unroll
        for (int nt = 0; nt < 16; ++nt) {
            short8 bfr = Bbase[(nt * 16 + col) * 32 + kc * 4 + q];
            acc[nt] = __builtin_amdgcn_mfma_f32_16x16x32_bf16(af, bfr, acc[nt], 0, 0, 0);
        }
    }

    long dbase = (long)b * 4194304 + (long)n * 256 +
                 (long)(bm * 64 + wv * 16 + q * 4) * 8192 + col;
    #pragma unroll
    for (int nt = 0; nt < 16; ++nt)
        #pragma unroll
        for (int r = 0; r < 4; ++r)
            P[dbase + (long)r * 8192 + nt * 16] = acc[nt][r];
}

// ---------------- GroupNorm: single-kernel (small) ----------------
__global__ __launch_bounds__(1024) void gn_relu_k(
    float* __restrict__ buf, const void* __restrict__ g, const void* __restrict__ bt,
    int C, int S, int groups, const int* __restrict__ flagp)
{
    int bf = *flagp;
    int nt = blockDim.x;
    int gid = blockIdx.x;
    int b = gid / groups, gr = gid % groups;
    int cpg = C / groups;
    long cnt = (long)cpg * S;
    float* base = buf + ((long)b * C + (long)gr * cpg) * S;
    double s = 0.0, s2 = 0.0;
    for (long i = threadIdx.x; i < cnt; i += nt) {
        float v = base[i];
        s += v; s2 += (double)v * v;
    }
    __shared__ double rs[1024], rq[1024];
    rs[threadIdx.x] = s; rq[threadIdx.x] = s2;
    __syncthreads();
    for (int off = nt >> 1; off > 0; off >>= 1) {
        if (threadIdx.x < off) { rs[threadIdx.x] += rs[threadIdx.x + off]; rq[threadIdx.x] += rq[threadIdx.x + off]; }
        __syncthreads();
    }
    double mean_d = rs[0] / (double)cnt;
    float mean = (float)mean_d;
    float var = (float)(rq[0] / (double)cnt - mean_d * mean_d);
    float rstd = rsqrtf(var + 1e-5f);
    for (long i = threadIdx.x; i < cnt; i += nt) {
        int c = gr * cpg + (int)(i / S);
        float v = (base[i] - mean) * rstd * ldin(g, c, bf) + ldin(bt, c, bf);
        base[i] = v > 0.f ? v : 0.f;
    }
}

// ---------------- GroupNorm: two-phase (large) ----------------
__global__ __launch_bounds__(256) void gn_part_k(
    const float* __restrict__ buf, double* __restrict__ part,
    int C, int S, int groups, int chunks)
{
    int gi = blockIdx.x / chunks, ch = blockIdx.x % chunks;
    int b = gi / groups, gr = gi % groups;
    int cpg = C / groups;
    long cnt = (long)cpg * S;
    long clen = cnt / chunks;
    const float* base = buf + ((long)b * C + (long)gr * cpg) * S + (long)ch * clen;
    double s = 0.0, s2 = 0.0;
    for (long i = threadIdx.x; i < clen; i += 256) {
        float v = base[i];
        s += v; s2 += (double)v * v;
    }
    __shared__ double rs[256], rq[256];
    rs[threadIdx.x] = s; rq[threadIdx.x] = s2;
    __syncthreads();
    for (int off = 128; off > 0; off >>= 1) {
        if (threadIdx.x < off) { rs[threadIdx.x] += rs[threadIdx.x + off]; rq[threadIdx.x] += rq[threadIdx.x + off]; }
        __syncthreads();
    }
    if (threadIdx.x == 0) { part[blockIdx.x * 2] = rs[0]; part[blockIdx.x * 2 + 1] = rq[0]; }
}

__global__ __launch_bounds__(256) void gn_apply_k(
    float* __restrict__ buf, const double* __restrict__ part,
    const void* __restrict__ g, const void* __restrict__ bt,
    int C, int S, int groups, int chunks, const int* __restrict__ flagp)
{
    int bf = *flagp;
    int gi = blockIdx.x / chunks, ch = blockIdx.x % chunks;
    int b = gi / groups, gr = gi % groups;
    int cpg = C / groups;
    long cnt = (long)cpg * S;
    long clen = cnt / chunks;
    double s = 0.0, s2 = 0.0;
    for (int k = 0; k < chunks; ++k) {
        s += part[(gi * chunks + k) * 2];
        s2 += part[(gi * chunks + k) * 2 + 1];
    }
    double mean_d = s / (double)cnt;
    float mean = (float)mean_d;
    float var = (float)(s2 / (double)cnt - mean_d * mean_d);
    float rstd = rsqrtf(var + 1e-5f);
    float* base = buf + ((long)b * C + (long)gr * cpg) * S + (long)ch * clen;
    long off0 = (long)ch * clen;
    for (long i = threadIdx.x; i < clen; i += 256) {
        int c = gr * cpg + (int)((off0 + i) / S);
        float v = (base[i] - mean) * rstd * ldin(g, c, bf) + ldin(bt, c, bf);
        base[i] = v > 0.f ? v : 0.f;
    }
}

// ---------------- sparse mask table ----------------
__global__ __launch_bounds__(384) void build_table_k(
    const void* __restrict__ mask, int* __restrict__ tabd,
    float* __restrict__ tabw, const int* __restrict__ flagp)
{
    int bf = *flagp;
    int nw = blockIdx.x;
    int w = nw >> 5, n = nw & 31;
    int tid = threadIdx.x;
    int d = tid - 165;
    float v = 0.f;
    if (d <= 165) {
        if (d < 0) v = ldin(mask, (long)(254 + d) * 65536 + ((long)n * 256 + 254) * 8 + w, bf);
        else       v = ldin(mask, (long)(1 + d) * 65536 + ((long)n * 256 + 1) * 8 + w, bf);
    }
    __shared__ unsigned char nz[384];
    nz[tid] = (v != 0.f) ? 1 : 0;
    if (tid < 6) { tabd[nw * 6 + tid] = 0; tabw[nw * 6 + tid] = 0.f; }
    __syncthreads();
    if (v != 0.f) {
        int slot = 0;
        for (int j = 0; j < tid; ++j) slot += nz[j];
        if (slot < 6) { tabd[nw * 6 + slot] = d; tabw[nw * 6 + slot] = v; }
    }
}

__global__ void build_corr_k(const void* __restrict__ mask, const int* __restrict__ tabd,
                             const float* __restrict__ tabw, float* __restrict__ corrB,
                             const int* __restrict__ flagp) {
    int bf = *flagp;
    int idx = blockIdx.x * 256 + threadIdx.x;   // 65536
    if (idx >= 65536) return;
    int n = idx >> 11, p = idx & 2047;
    int t = p >> 3, w = p & 7;
    float mv = ldin(mask, ((long)n * 256 + t) * 8 + w, bf);
    float sub = 0.f;
    int base = (w * 32 + n) * 6;
    for (int k = 0; k < 6; ++k)
        if (tabd[base + k] == -t && tabw[base + k] != 0.f) sub += tabw[base + k];
    corrB[idx] = mv - sub;
}

// partial apply: block = (h3, half); 16 n-values staged; writes part[half] (no bias)
__global__ __launch_bounds__(256) void apply_y_k(
    const float* __restrict__ P, const int* __restrict__ tabd,
    const float* __restrict__ tabw, float* __restrict__ part,
    const int* __restrict__ flagp)
{
    int bx = blockIdx.x;                 // 0..1023
    int h3 = bx >> 1, half = bx & 1;
    int n0 = half * 16;
    __shared__ float2 Pl2[16 * 256];     // 32 KB
    __shared__ float4 Tp4[384];          // 6 KB
    const float4* p04 = (const float4*)(P + ((long)h3 * 32 + n0) * 256);
    const float4* p14 = (const float4*)(P + ((long)(512 + h3) * 32 + n0) * 256);
    float4* pl4 = (float4*)Pl2;
    for (int i = threadIdx.x; i < 1024; i += 256) {
        float4 a = p04[i], b = p14[i];
        pl4[i * 2]     = make_float4(a.x, b.x, a.y, b.y);
        pl4[i * 2 + 1] = make_float4(a.z, b.z, a.w, b.w);
    }
    float2* tp2 = (float2*)Tp4;
    for (int i = threadIdx.x; i < 768; i += 256) {
        int el = i / 6, k = i - el * 6;
        int ge = ((el >> 4) << 5) + n0 + (el & 15);
        tp2[i] = make_float2(tabw[ge * 6 + k], __int_as_float(tabd[ge * 6 + k]));
    }
    __syncthreads();

    int t = threadIdx.x;
    float a0[8], a1[8];
    #pragma unroll
    for (int w = 0; w < 8; ++w) { a0[w] = 0.f; a1[w] = 0.f; }

    #pragma unroll 1
    for (int nl = 0; nl < 16; ++nl) {
        const float2* Pn = Pl2 + (nl << 8);
        #pragma unroll
        for (int w = 0; w < 8; ++w) {
            int e4 = ((w << 4) + nl) * 3;
            float4 q0 = Tp4[e4], q1 = Tp4[e4 + 1], q2 = Tp4[e4 + 2];
            float wts[6] = {q0.x, q0.z, q1.x, q1.z, q2.x, q2.z};
            int   dss[6] = {__float_as_int(q0.y), __float_as_int(q0.w),
                            __float_as_int(q1.y), __float_as_int(q1.w),
                            __float_as_int(q2.y), __float_as_int(q2.w)};
            #pragma unroll
            for (int k = 0; k < 6; ++k) {
                int tau = t + dss[k];
                int idx = tau & 255;
                float wt = ((unsigned)tau < 256u) ? wts[k] : 0.f;
                float2 pv = Pn[idx];
                a0[w] += wt * pv.x;
                a1[w] += wt * pv.y;
            }
        }
    }

    long y0 = (long)half * 2097152 + (long)h3 * 2048 + (long)t * 8;
    long y1 = y0 + 512L * 2048;
    *(float4*)(part + y0)     = make_float4(a0[0], a0[1], a0[2], a0[3]);
    *(float4*)(part + y0 + 4) = make_float4(a0[4], a0[5], a0[6], a0[7]);
    *(float4*)(part + y1)     = make_float4(a1[0], a1[1], a1[2], a1[3]);
    *(float4*)(part + y1 + 4) = make_float4(a1[4], a1[5], a1[6], a1[7]);
}

// y = part0 + part1 + r3b[h3] + sum_n P[b,h3,n,0] * corrB[n,p]   (corr fused)
__global__ void merge_y_k(const float* __restrict__ part, const float* __restrict__ P,
                          const float* __restrict__ corrB, float* __restrict__ y,
                          const void* __restrict__ r3b, const int* __restrict__ flagp) {
    int bf = *flagp;
    int i = blockIdx.x * 256 + threadIdx.x;   // 524288 float4
    if (i >= 524288) return;
    const float4* p4 = (const float4*)part;
    float4 a = p4[i], b = p4[i + 524288];
    long e = (long)i * 4;
    int bb_ = (int)(e >> 20);
    int h3 = (int)((e >> 11) & 511);
    int p = (int)(e & 2047);
    float bias = ldin(r3b, h3, bf);
    float4 acc = make_float4(a.x + b.x + bias, a.y + b.y + bias,
                             a.z + b.z + bias, a.w + b.w + bias);
    const float* p0 = P + ((long)(bb_ * 512 + h3) * 32) * 256;
    #pragma unroll 4
    for (int n = 0; n < 32; ++n) {
        float pv = p0[n * 256];
        float4 cb = *(const float4*)(corrB + n * 2048 + p);
        acc.x += pv * cb.x; acc.y += pv * cb.y;
        acc.z += pv * cb.z; acc.w += pv * cb.w;
    }
    ((float4*)y)[i] = acc;
}

__global__ __launch_bounds__(64) void head_out_k(
    const float* __restrict__ t1s, const float* __restrict__ t1e,
    const void* __restrict__ s2w, const void* __restrict__ s2b,
    const void* __restrict__ e2w, const void* __restrict__ e2b,
    void* __restrict__ out, const int* __restrict__ flagp) {
    int bf = *flagp;
    int idx = blockIdx.x * 64 + threadIdx.x;   // 4096
    if (idx >= 4096) return;
    int b = idx >> 11, p = idx & 2047;
    const float* ts = t1s + (long)b * 262144 + p;
    const float* te = t1e + (long)b * 262144 + p;
    float as = ldin(s2b, 0, bf), ae = ldin(e2b, 0, bf);
    #pragma unroll 8
    for (int c = 0; c < 128; ++c) {
        as += ldin(s2w, c, bf) * ts[(long)c * 2048];
        ae += ldin(e2w, c, bf) * te[(long)c * 2048];
    }
    float vs = 1.f / (1.f + expf(-as));
    float ve = 1.f / (1.f + expf(-ae));
    long o0 = ((long)b * 2) * 2048 + p;
    long o1 = ((long)b * 2 + 1) * 2048 + p;
    if (bf) {
        ((bf16*)out)[o0] = __float2bfloat16(vs);
        ((bf16*)out)[o1] = __float2bfloat16(ve);
    } else {
        ((float*)out)[o0] = vs;
        ((float*)out)[o1] = ve;
    }
}

// ---------------- launch ----------------
extern "C" void kernel_launch(void* const* d_in, const int* in_sizes, int n_in,
                              void* d_out, int out_size, void* d_ws, size_t ws_size,
                              hipStream_t stream) {
    const void* x    = d_in[0];
    const void* mask = d_in[1];
    const void* c1w  = d_in[2];
    const void* c1b  = d_in[3];
    const void* gn1g = d_in[4];
    const void* gn1b = d_in[5];
    const void* w3   = d_in[6];
    const void* r3b  = d_in[7];
    const void* gn3g = d_in[8];
    const void* gn3b = d_in[9];
    const void* w2   = d_in[10];
    const void* r2b  = d_in[11];
    const void* gn2g = d_in[12];
    const void* gn2b = d_in[13];
    const void* s1w  = d_in[14];
    const void* s1b  = d_in[15];
    const void* sgng = d_in[16];
    const void* sgnb = d_in[17];
    const void* s2w  = d_in[18];
    const void* s2b  = d_in[19];
    const void* e1w  = d_in[20];
    const void* e1b  = d_in[21];
    const void* egng = d_in[22];
    const void* egnb = d_in[23];
    const void* e2w  = d_in[24];
    const void* e2b  = d_in[25];
    float* ws = (float*)d_ws;

    int*   flagI = (int*)(ws + 0);       // 64 reserved
    float* h     = ws + 64;              // 131072
    float* c1t   = ws + 131136;          // 393216 (c1wb bf16)
    float* w2t   = ws + 524352;          // 65536 (w2b bf16)
    float* s1t   = ws + 589888;          // 294912 (s1wb+e1wb bf16)
    float* corrB = ws + 884800;          // 65536
    float* tabw  = ws + 950336;          // 1536
    int*   tabd  = (int*)(ws + 951872);  // 1536
    float* t1s   = ws + 986176;          // 524288
    float* t1e   = ws + 1510464;         // 524288
    float* f     = ws + 2034752;         // 524288
    float* y     = ws + 2559040;         // 2097152
    float* w3reg = ws + 4656192;         // 4194304 (bf16 bufs / apply partials)
    float* Pb    = ws + 8850496;         // 8388608
    double* gnbuf = (double*)(ws + 17239104); // 1024 doubles
    bf16*  w3b   = (bf16*)w3reg;
    bf16*  hbT   = (bf16*)(w3reg + 2097152);
    bf16*  c1wb  = (bf16*)c1t;
    bf16*  w2b   = (bf16*)w2t;
    bf16*  hwb   = (bf16*)s1t;
    bf16*  colxb = (bf16*)y;                       // y dead until merge
    bf16*  fcolb = (bf16*)Pb;
    bf16*  yT    = (bf16*)(Pb + 4194304);          // Pb tail (P dead post-merge)
    float* ypart = w3reg;                          // 4M floats (w3b/hbT dead post-pgemm)

    dim3 blk(256);
    dim3 blkG(1024);

    detect_k<<<dim3(1), blk, 0, stream>>>((const unsigned short*)x, flagI);

    // weight prep + table extraction
    cast_bf_k<<<dim3(1536), blk, 0, stream>>>(c1w, c1wb, 393216, flagI);
    cast_bf_k<<<dim3(576),  blk, 0, stream>>>(s1w, hwb, 147456, flagI);
    cast_bf_k<<<dim3(576),  blk, 0, stream>>>(e1w, hwb + 147456, 147456, flagI);
    cast_bf_k<<<dim3(256),  blk, 0, stream>>>(w2, w2b, 65536, flagI);
    transpose_w3b_k<<<dim3(512), blk, 0, stream>>>(w3, w3b, flagI);
    build_table_k<<<dim3(256), dim3(384), 0, stream>>>(mask, tabd, tabw, flagI);
    build_corr_k<<<dim3(256), blk, 0, stream>>>(mask, tabd, tabw, corrB, flagI);

    // conv1 via MFMA + GN1 + ReLU
    im2col_xb_k<<<dim3(3072), blk, 0, stream>>>(x, colxb, flagI);
    wgemm_mfma<1><<<dim3(16, 4, 2), blk, 0, stream>>>(
        c1wb, colxb, h, c1b, c1b, 256, 1536, 256, 1, 0L, flagI);
    gn_relu_k<<<dim3(64), blkG, 0, stream>>>(h, gn1g, gn1b, 256, 256, 32, flagI);

    // P-GEMM via bf16 MFMA
    cast_hT_k<<<dim3(512), blk, 0, stream>>>(h, hbT);
    pgemm_mfma<<<dim3(1, 8, 64), blk, 0, stream>>>(w3b, hbT, Pb);

    // sparse mask apply + fused merge(bias + corr) + GN3 (2-phase)
    apply_y_k<<<dim3(1024), blk, 0, stream>>>(Pb, tabd, tabw, ypart, flagI);
    merge_y_k<<<dim3(2048), blk, 0, stream>>>(ypart, Pb, corrB, y, r3b, flagI);
    gn_part_k<<<dim3(512), blk, 0, stream>>>(y, gnbuf, 512, 2048, 32, 8);
    gn_apply_k<<<dim3(512), blk, 0, stream>>>(y, gnbuf, gn3g, gn3b, 512, 2048, 32, 8, flagI);

    // r2d via MFMA: cast-transpose y -> yT bf16, wgemm (bias fused) + GN2 (2-phase)
    castT_k<<<dim3(32, 8, 2), blk, 0, stream>>>(y, yT);
    wgemm_mfma<2><<<dim3(64, 2, 2), blk, 0, stream>>>(
        w2b, yT, f, r2b, r2b, 128, 512, 2048, 2, 0L, flagI);
    gn_part_k<<<dim3(256), blk, 0, stream>>>(f, gnbuf, 128, 2048, 32, 4);
    gn_apply_k<<<dim3(256), blk, 0, stream>>>(f, gnbuf, gn2g, gn2b, 128, 2048, 32, 4, flagI);

    // heads via MFMA (tiled im2col) + GN (2-phase each)
    im2col_fb_t<<<dim3(32, 4, 2), blk, 0, stream>>>(f, fcolb);
    wgemm_mfma<4><<<dim3(32, 2, 4), blk, 0, stream>>>(
        hwb, fcolb, t1s, s1b, e1b, 128, 1152, 2048, 2, 147456L, flagI);
    gn_part_k<<<dim3(256), blk, 0, stream>>>(t1s, gnbuf, 128, 2048, 32, 4);
    gn_apply_k<<<dim3(256), blk, 0, stream>>>(t1s, gnbuf, sgng, sgnb, 128, 2048, 32, 4, flagI);
    gn_part_k<<<dim3(256), blk, 0, stream>>>(t1e, gnbuf, 128, 2048, 32, 4);
    gn_apply_k<<<dim3(256), blk, 0, stream>>>(t1e, gnbuf, egng, egnb, 128, 2048, 32, 4, flagI);

    // 1x1 head convs + sigmoid -> output
    head_out_k<<<dim3(64), dim3(64), 0, stream>>>(t1s, t1e, s2w, s2b, e2w, e2b, d_out, flagI);
}